// Round 1
// baseline (613.868 us; speedup 1.0000x reference)
//
#include <hip/hip_runtime.h>
#include <math.h>

#define NB 8
#define CIN 512
#define CM 32
#define MG 8
#define HH 128
#define WW 128
#define HWSZ (HH*WW)
#define EPSF 1e-5f
#define COT_ITAU 1.25f   // 1/0.8
#define LAM 0.7f
#define GFLOOR 0.05f

__device__ __forceinline__ float wsum(float v){
#pragma unroll
  for (int o = 32; o; o >>= 1) v += __shfl_xor(v, o, 64);
  return v;
}

// transpose compress weights [32][512] -> [512][32] for consecutive scalar loads
__global__ void k_tw(const float* __restrict__ w, float* __restrict__ wT){
  int i = blockIdx.x*256 + threadIdx.x;
  if (i < CM*CIN){
    int c = i >> 9, k = i & (CIN-1);
    wT[k*CM + c] = w[i];
  }
}

// compress conv (512->32) + per-(b,c) sum/sumsq stats. y stored PRE-norm.
__global__ __launch_bounds__(256) void k_compress(
    const float* __restrict__ x, const float* __restrict__ wT,
    float* __restrict__ y, float* __restrict__ s1, float* __restrict__ s2)
{
  int tid = threadIdx.x;
  int b = blockIdx.x >> 6;
  int p = ((blockIdx.x & 63) << 8) + tid;
  const float* xb = x + ((size_t)b*CIN)*HWSZ + p;
  float acc[CM];
#pragma unroll
  for (int c=0;c<CM;c++) acc[c]=0.f;
  for (int i=0;i<CIN;i++){
    float xv = xb[(size_t)i*HWSZ];
    const float* wr = wT + i*CM;     // uniform address -> scalar loads
#pragma unroll
    for (int c=0;c<CM;c++) acc[c] = fmaf(wr[c], xv, acc[c]);
  }
  float* yb = y + ((size_t)b*CM)*HWSZ + p;
#pragma unroll
  for (int c=0;c<CM;c++) yb[(size_t)c*HWSZ] = acc[c];
  float ms=0.f, mq=0.f;
#pragma unroll
  for (int c=0;c<CM;c++){
    float s = wsum(acc[c]);
    float q = wsum(acc[c]*acc[c]);
    if ((tid&63)==c){ ms=s; mq=q; }
  }
  int lane = tid & 63;
  if (lane < CM){
    atomicAdd(&s1[b*CM+lane], ms);
    atomicAdd(&s2[b*CM+lane], mq);
  }
}

// sums -> premultiplied affine: xc = y*A + B  (then relu at consumer)
__global__ void k_finalize(const float* __restrict__ s1, const float* __restrict__ s2,
    const float* __restrict__ g, const float* __restrict__ bi,
    float* __restrict__ A, float* __restrict__ Bo, float cnt)
{
  int i = threadIdx.x;
  if (i < NB*CM){
    int c = i & (CM-1);
    float mu = s1[i]/cnt;
    float var = s2[i]/cnt - mu*mu;
    float a = rsqrtf(var+EPSF)*g[c];
    A[i]=a; Bo[i]=bi[c]-mu*a;
  }
}

__global__ void k_pool_w(const float* __restrict__ y, const float* __restrict__ A,
                         const float* __restrict__ Bo, float* __restrict__ wpool){
  int idx = blockIdx.x*256+threadIdx.x;
  if (idx >= NB*CM*WW) return;
  int w = idx & (WW-1);
  int bc = idx >> 7;
  const float* col = y + (size_t)bc*HWSZ + w;
  float a=A[bc], bb=Bo[bc], s=0.f;
  for (int h=0;h<HH;h++) s += fmaxf(0.f, fmaf(col[h*WW], a, bb));
  wpool[idx] = s*(1.0f/HH);
}

__global__ void k_pool_h(const float* __restrict__ y, const float* __restrict__ A,
                         const float* __restrict__ Bo, float* __restrict__ hpool){
  int idx = blockIdx.x*256+threadIdx.x;
  if (idx >= NB*CM*HH) return;
  int h = idx & (HH-1);
  int bc = idx >> 7;
  const float4* row = (const float4*)(y + (size_t)bc*HWSZ + h*WW);
  float a=A[bc], bb=Bo[bc], s=0.f;
  for (int k=0;k<WW/4;k++){
    float4 t = row[k];
    s += fmaxf(0.f, fmaf(t.x,a,bb)) + fmaxf(0.f, fmaf(t.y,a,bb))
       + fmaxf(0.f, fmaf(t.z,a,bb)) + fmaxf(0.f, fmaf(t.w,a,bb));
  }
  hpool[idx] = s*(1.0f/WW);
}

// coord branch MLP: block per (b, path). 128 threads = positions.
__global__ __launch_bounds__(128) void k_coord(
    const float* __restrict__ hpool, const float* __restrict__ wpool,
    const float* __restrict__ w1, const float* __restrict__ g1, const float* __restrict__ b1,
    const float* __restrict__ hw_, const float* __restrict__ hb_,
    const float* __restrict__ ww_, const float* __restrict__ wb_,
    float* __restrict__ ah, float* __restrict__ aw)
{
  __shared__ float T[CM][HH+1];
  __shared__ float sa[CM], sb[CM], smx[CM], ssc[CM];
  int tid = threadIdx.x;
  int b = blockIdx.x >> 1;
  int path = blockIdx.x & 1;
  const float* pool = (path==0)? hpool : wpool;
  const float* w2   = (path==0)? hw_ : ww_;
  const float* b2   = (path==0)? hb_ : wb_;
  float* outp       = (path==0)? ah : aw;

  float in[CM];
#pragma unroll
  for (int c=0;c<CM;c++) in[c] = pool[(b*CM+c)*HH + tid];
#pragma unroll
  for (int gI=0;gI<4;gI++)
#pragma unroll
    for (int o=0;o<MG;o++){
      float s=0.f;
#pragma unroll
      for (int i=0;i<MG;i++) s = fmaf(w1[gI*64+o*8+i], in[gI*8+i], s);
      T[gI*8+o][tid] = s;
    }
  __syncthreads();
  if (tid < CM){
    float s=0.f, q=0.f;
    for (int k=0;k<HH;k++){ float t=T[tid][k]; s+=t; q+=t*t; }
    float mu = s*(1.0f/HH);
    float var = q*(1.0f/HH) - mu*mu;
    float a = rsqrtf(var+EPSF)*g1[tid];
    sa[tid]=a; sb[tid]=b1[tid]-mu*a;
  }
  __syncthreads();
  float z[CM];
  {
    float sil[CM];
#pragma unroll
    for (int c=0;c<CM;c++){
      float val = fmaf(T[c][tid], sa[c], sb[c]);
      sil[c] = val/(1.f+__expf(-val));
    }
#pragma unroll
    for (int gI=0;gI<4;gI++)
#pragma unroll
      for (int o=0;o<MG;o++){
        float s=b2[gI*8+o];
#pragma unroll
        for (int i=0;i<MG;i++) s = fmaf(w2[gI*64+o*8+i], sil[gI*8+i], s);
        z[gI*8+o]=s;
      }
  }
  __syncthreads();
#pragma unroll
  for (int c=0;c<CM;c++) T[c][tid]=z[c];
  __syncthreads();
  if (tid < CM){
    float mx=-1e30f;
    for (int k=0;k<HH;k++) mx = fmaxf(mx, T[tid][k]);
    float s=0.f;
    for (int k=0;k<HH;k++) s += __expf(T[tid][k]-mx);
    smx[tid]=mx; ssc[tid]=(float)HH/s;
  }
  __syncthreads();
#pragma unroll
  for (int c=0;c<CM;c++)
    outp[(b*CM+c)*HH + tid] = __expf(T[c][tid]-smx[c])*ssc[c];
}

// CoT part 1: k1, v, att_pre (+ att stats)
__global__ __launch_bounds__(256) void k_cot1(
  const float* __restrict__ y, const float* __restrict__ A, const float* __restrict__ Bo,
  const float* __restrict__ kw, const float* __restrict__ vw, const float* __restrict__ a1w,
  float* __restrict__ k1o, float* __restrict__ vo, float* __restrict__ ao,
  float* __restrict__ s1, float* __restrict__ s2)
{
  int tid=threadIdx.x;
  int b = blockIdx.x >> 6;
  int p = ((blockIdx.x&63)<<8)+tid;
  size_t base = ((size_t)b*CM)*HWSZ + p;
  float xc[CM], k1[CM], vv[CM], at[CM];
#pragma unroll
  for (int c=0;c<CM;c++)
    xc[c] = fmaxf(0.f, fmaf(y[base+(size_t)c*HWSZ], A[b*CM+c], Bo[b*CM+c]));
#pragma unroll
  for (int gI=0;gI<4;gI++)
#pragma unroll
    for (int o=0;o<MG;o++){
      float sk=0.f, sv=0.f;
#pragma unroll
      for (int i=0;i<MG;i++){
        float xv = xc[gI*MG+i];
        sk = fmaf(kw[gI*64+o*8+i], xv, sk);
        sv = fmaf(vw[gI*64+o*8+i], xv, sv);
      }
      k1[gI*MG+o]=sk; vv[gI*MG+o]=sv;
    }
  // att1: y=concat(k1,xc), regrouped by 16
#pragma unroll
  for (int gI=0;gI<4;gI++)
#pragma unroll
    for (int o=0;o<MG;o++){
      float s=0.f;
#pragma unroll
      for (int i=0;i<16;i++){
        float inp = (gI<2) ? k1[gI*16+i] : xc[(gI-2)*16+i];
        s = fmaf(a1w[gI*128+o*16+i], inp, s);
      }
      at[gI*MG+o]=s;
    }
#pragma unroll
  for (int c=0;c<CM;c++){
    k1o[base+(size_t)c*HWSZ]=k1[c];
    vo [base+(size_t)c*HWSZ]=vv[c];
    ao [base+(size_t)c*HWSZ]=at[c];
  }
  float ms=0.f,mq=0.f;
#pragma unroll
  for (int c=0;c<CM;c++){
    float s=wsum(at[c]); float q=wsum(at[c]*at[c]);
    if ((tid&63)==c){ms=s;mq=mq=q;}
  }
  int lane=tid&63;
  if (lane<CM){ atomicAdd(&s1[b*CM+lane],ms); atomicAdd(&s2[b*CM+lane],mq); }
}

// CoT part 2: logits + expsum (no max subtraction: values bounded, exact same math)
__global__ __launch_bounds__(256) void k_cot2(
  const float* __restrict__ ao, const float* __restrict__ A, const float* __restrict__ Bo,
  const float* __restrict__ a2w, float* __restrict__ lg, float* __restrict__ es)
{
  int tid=threadIdx.x;
  int b = blockIdx.x >> 6;
  int p = ((blockIdx.x&63)<<8)+tid;
  size_t base = ((size_t)b*CM)*HWSZ + p;
  float att[CM], l[CM];
#pragma unroll
  for (int c=0;c<CM;c++)
    att[c] = fmaxf(0.f, fmaf(ao[base+(size_t)c*HWSZ], A[b*CM+c], Bo[b*CM+c]));
#pragma unroll
  for (int gI=0;gI<4;gI++)
#pragma unroll
    for (int o=0;o<MG;o++){
      float s=0.f;
#pragma unroll
      for (int i=0;i<MG;i++) s = fmaf(a2w[gI*64+o*8+i], att[gI*8+i], s);
      l[gI*MG+o]=s;
    }
#pragma unroll
  for (int c=0;c<CM;c++) lg[base+(size_t)c*HWSZ]=l[c];
  float ms=0.f;
#pragma unroll
  for (int c=0;c<CM;c++){
    float s = wsum(__expf(l[c]*COT_ITAU));
    if ((tid&63)==c) ms=s;
  }
  int lane=tid&63;
  if (lane<CM) atomicAdd(&es[b*CM+lane], ms);
}

// mix + cot_fuse + coord combine + fusion conv (+ fus stats)
__global__ __launch_bounds__(256) void k_mix_fuse(
  const float* __restrict__ y, const float* __restrict__ A, const float* __restrict__ Bo,
  const float* __restrict__ k1p, const float* __restrict__ vp, const float* __restrict__ lgp,
  const float* __restrict__ ah, const float* __restrict__ awp, const float* __restrict__ es,
  const float* __restrict__ alpha, const float* __restrict__ beta,
  const float* __restrict__ fw, const float* __restrict__ fuw,
  float* __restrict__ fpo, float* __restrict__ s1, float* __restrict__ s2)
{
  int tid=threadIdx.x;
  int b = blockIdx.x>>6;
  int p = ((blockIdx.x&63)<<8)+tid;
  int h = p >> 7, w = p & (WW-1);
  size_t base = ((size_t)b*CM)*HWSZ + p;
  float al=alpha[0], be=beta[0];
  float co[CM], t[CM];
#pragma unroll
  for (int c=0;c<CM;c++){
    float xc = fmaxf(0.f, fmaf(y[base+(size_t)c*HWSZ], A[b*CM+c], Bo[b*CM+c]));
    float lgv = lgp[base+(size_t)c*HWSZ];
    float sm = __expf(lgv*COT_ITAU) * (16384.f/es[b*CM+c]);
    float sg = 1.f/(1.f+__expf(-lgv));
    float mix = (1.f-LAM)*sg + LAM*sm;
    t[c] = fmaf(mix, vp[base+(size_t)c*HWSZ], k1p[base+(size_t)c*HWSZ]);
    float wl = al*ah[(b*CM+c)*HH + h] + be*awp[(b*CM+c)*WW + w];
    co[c] = xc * (1.0f + (wl - 1.0f));   // kappa = 1
  }
  float cot[CM];
#pragma unroll
  for (int o=0;o<CM;o++){
    float s=0.f;
#pragma unroll
    for (int i=0;i<CM;i++) s = fmaf(fw[o*CM+i], t[i], s);
    cot[o]=s;
  }
  float ms=0.f, mq=0.f;
#pragma unroll
  for (int o=0;o<CM;o++){
    float s=0.f;
#pragma unroll
    for (int i=0;i<CM;i++) s = fmaf(fuw[o*64+i], co[i], s);
#pragma unroll
    for (int i=0;i<CM;i++) s = fmaf(fuw[o*64+32+i], cot[i], s);
    fpo[base+(size_t)o*HWSZ]=s;
    float ss = wsum(s); float qq = wsum(s*s);
    if ((tid&63)==o){ ms=ss; mq=qq; }
  }
  int lane=tid&63;
  if (lane<CM){ atomicAdd(&s1[b*CM+lane],ms); atomicAdd(&s2[b*CM+lane],mq); }
}

// gate statistics: sum of relu(norm(fused_pre)) per (b,c)
__global__ __launch_bounds__(256) void k_gstat(const float4* __restrict__ fp,
  const float* __restrict__ A, const float* __restrict__ Bo, float* __restrict__ gsum)
{
  int idx = blockIdx.x*256+threadIdx.x;  // NB*CM*HWSZ/4
  int bc = idx >> 12;
  float a=A[bc], bb=Bo[bc];
  float4 tv = fp[idx];
  float s = fmaxf(0.f,fmaf(tv.x,a,bb))+fmaxf(0.f,fmaf(tv.y,a,bb))
          + fmaxf(0.f,fmaf(tv.z,a,bb))+fmaxf(0.f,fmaf(tv.w,a,bb));
  s = wsum(s);
  if ((threadIdx.x&63)==0) atomicAdd(&gsum[bc], s);
}

__global__ void k_gate(const float* __restrict__ gsum, const float* __restrict__ gw,
                       float* __restrict__ scale){
  int b = threadIdx.x;
  if (b < NB){
    float s=0.f;
    for (int c=0;c<CM;c++) s += gw[c]*gsum[b*CM+c];
    s *= (1.0f/HWSZ);
    float gt = 1.f/(1.f+__expf(-s));
    scale[b] = gt*(1.f-GFLOOR)+GFLOOR;
  }
}

// expand conv 32->512, norm+relu+gate applied inline
__global__ __launch_bounds__(256) void k_expand(const float* __restrict__ fp,
  const float* __restrict__ A, const float* __restrict__ Bo,
  const float* __restrict__ ew, const float* __restrict__ scale, float* __restrict__ out)
{
  int tid=threadIdx.x;
  int b = blockIdx.x>>6;
  int p = ((blockIdx.x&63)<<8)+tid;
  float sc = scale[b];
  float f[CM];
#pragma unroll
  for (int c=0;c<CM;c++)
    f[c] = fmaxf(0.f, fmaf(fp[((size_t)b*CM+c)*HWSZ+p], A[b*CM+c], Bo[b*CM+c]))*sc;
  size_t ob = ((size_t)b*CIN)*HWSZ + p;
  for (int o=0;o<CIN;o+=8){
    float acc[8];
#pragma unroll
    for (int j=0;j<8;j++) acc[j]=0.f;
#pragma unroll
    for (int c=0;c<CM;c++){
      float fv=f[c];
#pragma unroll
      for (int j=0;j<8;j++) acc[j]=fmaf(ew[(o+j)*CM+c],fv,acc[j]);
    }
#pragma unroll
    for (int j=0;j<8;j++) out[ob+(size_t)(o+j)*HWSZ]=acc[j];
  }
}

extern "C" void kernel_launch(void* const* d_in, const int* in_sizes, int n_in,
                              void* d_out, int out_size, void* d_ws, size_t ws_size,
                              hipStream_t stream)
{
  const float* x    = (const float*)d_in[0];
  const float* cw   = (const float*)d_in[1];
  const float* incg = (const float*)d_in[2];
  const float* incb = (const float*)d_in[3];
  const float* pjw  = (const float*)d_in[4];
  const float* pjg  = (const float*)d_in[5];
  const float* pjb  = (const float*)d_in[6];
  const float* chw  = (const float*)d_in[7];
  const float* chb  = (const float*)d_in[8];
  const float* cww  = (const float*)d_in[9];
  const float* cwb  = (const float*)d_in[10];
  const float* alpha= (const float*)d_in[11];
  const float* beta = (const float*)d_in[12];
  const float* kw   = (const float*)d_in[13];
  const float* vw   = (const float*)d_in[14];
  const float* a1w  = (const float*)d_in[15];
  const float* ag   = (const float*)d_in[16];
  const float* ab   = (const float*)d_in[17];
  const float* a2w  = (const float*)d_in[18];
  const float* fw   = (const float*)d_in[19];
  const float* fuw  = (const float*)d_in[20];
  const float* fg   = (const float*)d_in[21];
  const float* fb   = (const float*)d_in[22];
  const float* gw   = (const float*)d_in[23];
  const float* ew   = (const float*)d_in[24];
  float* out = (float*)d_out;

  float* ws = (float*)d_ws;
  const size_t BIG = (size_t)NB*CM*HWSZ;  // 4,194,304 floats
  float* y   = ws;
  float* P   = ws +   BIG;   // att_pre, later fused_pre
  float* k1  = ws + 2*BIG;
  float* v   = ws + 3*BIG;
  float* lg  = ws + 4*BIG;
  float* sm  = ws + 5*BIG;
  float* wT    = sm;  sm += CM*CIN;
  float* hpool = sm;  sm += NB*CM*HH;
  float* wpool = sm;  sm += NB*CM*WW;
  float* ahB   = sm;  sm += NB*CM*HH;
  float* awB   = sm;  sm += NB*CM*WW;
  float* acc   = sm;  sm += 8*256;   // zeroed accumulators
  float* statS = acc,      *statQ = acc+256;
  float* attS  = acc+512,  *attQ  = acc+768;
  float* esum  = acc+1024;
  float* fusS  = acc+1280, *fusQ  = acc+1536;
  float* gsum  = acc+1792;
  float* normA = sm; sm+=256; float* normB = sm; sm+=256;
  float* attA  = sm; sm+=256; float* attB  = sm; sm+=256;
  float* fusA  = sm; sm+=256; float* fusB  = sm; sm+=256;
  float* scale = sm; sm+=64;

  hipMemsetAsync(acc, 0, 8*256*sizeof(float), stream);
  k_tw<<<64,256,0,stream>>>(cw, wT);
  k_compress<<<512,256,0,stream>>>(x, wT, y, statS, statQ);
  k_finalize<<<1,256,0,stream>>>(statS,statQ,incg,incb,normA,normB,(float)HWSZ);
  k_pool_w<<<128,256,0,stream>>>(y,normA,normB,wpool);
  k_pool_h<<<128,256,0,stream>>>(y,normA,normB,hpool);
  k_coord<<<16,128,0,stream>>>(hpool,wpool,pjw,pjg,pjb,chw,chb,cww,cwb,ahB,awB);
  k_cot1<<<512,256,0,stream>>>(y,normA,normB,kw,vw,a1w,k1,v,P,attS,attQ);
  k_finalize<<<1,256,0,stream>>>(attS,attQ,ag,ab,attA,attB,(float)HWSZ);
  k_cot2<<<512,256,0,stream>>>(P,attA,attB,a2w,lg,esum);
  k_mix_fuse<<<512,256,0,stream>>>(y,normA,normB,k1,v,lg,ahB,awB,esum,alpha,beta,fw,fuw,P,fusS,fusQ);
  k_finalize<<<1,256,0,stream>>>(fusS,fusQ,fg,fb,fusA,fusB,(float)HWSZ);
  k_gstat<<<4096,256,0,stream>>>((const float4*)P, fusA,fusB,gsum);
  k_gate<<<1,64,0,stream>>>(gsum,gw,scale);
  k_expand<<<512,256,0,stream>>>(P,fusA,fusB,ew,scale,out);
}

// Round 2
// 462.472 us; speedup vs baseline: 1.3274x; 1.3274x over previous
//
#include <hip/hip_runtime.h>
#include <math.h>

#define NB 8
#define CIN 512
#define CM 32
#define MG 8
#define HH 128
#define WW 128
#define HWSZ (HH*WW)
#define EPSF 1e-5f
#define COT_ITAU 1.25f   // 1/0.8
#define LAM 0.7f
#define GFLOOR 0.05f

__device__ __forceinline__ float wsum(float v){
#pragma unroll
  for (int o = 32; o; o >>= 1) v += __shfl_xor(v, o, 64);
  return v;
}

// transpose compress weights [32][512] -> [512][32]
__global__ void k_tw(const float* __restrict__ w, float* __restrict__ wT){
  int i = blockIdx.x*256 + threadIdx.x;
  if (i < CM*CIN){
    int c = i >> 9, k = i & (CIN-1);
    wT[k*CM + c] = w[i];
  }
}

// compress conv (512->32), K-split over input-channel halves (blockIdx.y).
__global__ __launch_bounds__(256) void k_compress(
    const float* __restrict__ x, const float* __restrict__ wT,
    float* __restrict__ part)          // part[half][B][CM][HW] via pointer offset
{
  int tid = threadIdx.x;
  int b = blockIdx.x >> 6;
  int p = ((blockIdx.x & 63) << 8) + tid;
  int half = blockIdx.y;
  const float* xb = x + ((size_t)b*CIN + half*256)*HWSZ + p;
  const float* wh = wT + half*256*CM;
  float acc[CM];
#pragma unroll
  for (int c=0;c<CM;c++) acc[c]=0.f;
  for (int i=0;i<256;i+=4){
    float x0 = xb[(size_t)(i+0)*HWSZ];
    float x1 = xb[(size_t)(i+1)*HWSZ];
    float x2 = xb[(size_t)(i+2)*HWSZ];
    float x3 = xb[(size_t)(i+3)*HWSZ];
    const float* w0 = wh + (i+0)*CM;
    const float* w1 = wh + (i+1)*CM;
    const float* w2 = wh + (i+2)*CM;
    const float* w3 = wh + (i+3)*CM;
#pragma unroll
    for (int c=0;c<CM;c++)
      acc[c] = fmaf(w0[c],x0, fmaf(w1[c],x1, fmaf(w2[c],x2, fmaf(w3[c],x3, acc[c]))));
  }
  float* yb = part + (size_t)half*NB*CM*HWSZ + ((size_t)b*CM)*HWSZ + p;
#pragma unroll
  for (int c=0;c<CM;c++) yb[(size_t)c*HWSZ] = acc[c];
}

// combine halves -> y, plus per-(b,c) sum/sumsq stats
__global__ __launch_bounds__(256) void k_comb(
    const float4* __restrict__ p0, const float4* __restrict__ p1,
    float4* __restrict__ y, float* __restrict__ s1, float* __restrict__ s2)
{
  int idx = blockIdx.x*256 + threadIdx.x;       // over NB*CM*HWSZ/4
  float4 a = p0[idx], bq = p1[idx];
  a.x+=bq.x; a.y+=bq.y; a.z+=bq.z; a.w+=bq.w;
  y[idx] = a;
  int bc = idx >> 12;                           // 4096 float4 per (b,c)
  float s = a.x+a.y+a.z+a.w;
  float q = a.x*a.x+a.y*a.y+a.z*a.z+a.w*a.w;
  s = wsum(s); q = wsum(q);
  if ((threadIdx.x&63)==0){ atomicAdd(&s1[bc],s); atomicAdd(&s2[bc],q); }
}

// sums -> premultiplied affine: xc = y*A + B
__global__ void k_finalize(const float* __restrict__ s1, const float* __restrict__ s2,
    const float* __restrict__ g, const float* __restrict__ bi,
    float* __restrict__ A, float* __restrict__ Bo, float cnt)
{
  int i = threadIdx.x;
  if (i < NB*CM){
    int c = i & (CM-1);
    float mu = s1[i]/cnt;
    float var = s2[i]/cnt - mu*mu;
    float a = rsqrtf(var+EPSF)*g[c];
    A[i]=a; Bo[i]=bi[c]-mu*a;
  }
}

__global__ void k_pool_w(const float* __restrict__ y, const float* __restrict__ A,
                         const float* __restrict__ Bo, float* __restrict__ wpool){
  int idx = blockIdx.x*256+threadIdx.x;
  if (idx >= NB*CM*WW) return;
  int w = idx & (WW-1);
  int bc = idx >> 7;
  const float* col = y + (size_t)bc*HWSZ + w;
  float a=A[bc], bb=Bo[bc], s=0.f;
  for (int h=0;h<HH;h++) s += fmaxf(0.f, fmaf(col[h*WW], a, bb));
  wpool[idx] = s*(1.0f/HH);
}

// one wave per row: coalesced
__global__ __launch_bounds__(256) void k_pool_h(const float* __restrict__ y,
    const float* __restrict__ A, const float* __restrict__ Bo, float* __restrict__ hpool){
  int tid = threadIdx.x;
  int r = blockIdx.x*4 + (tid>>6);     // row over NB*CM*HH
  int lane = tid & 63;
  const float2* rp = (const float2*)(y + (size_t)r*WW);
  float2 v = rp[lane];
  int bc = r >> 7;
  float a=A[bc], bb=Bo[bc];
  float s = fmaxf(0.f, fmaf(v.x,a,bb)) + fmaxf(0.f, fmaf(v.y,a,bb));
  s = wsum(s);
  if (lane==0) hpool[r] = s*(1.0f/WW);
}

// coord branch MLP: block per (b, path). 128 threads = positions.
__global__ __launch_bounds__(128) void k_coord(
    const float* __restrict__ hpool, const float* __restrict__ wpool,
    const float* __restrict__ w1, const float* __restrict__ g1, const float* __restrict__ b1,
    const float* __restrict__ hw_, const float* __restrict__ hb_,
    const float* __restrict__ ww_, const float* __restrict__ wb_,
    float* __restrict__ ah, float* __restrict__ aw)
{
  __shared__ float T[CM][HH+1];
  __shared__ float sa[CM], sb[CM], smx[CM], ssc[CM];
  int tid = threadIdx.x;
  int b = blockIdx.x >> 1;
  int path = blockIdx.x & 1;
  const float* pool = (path==0)? hpool : wpool;
  const float* w2   = (path==0)? hw_ : ww_;
  const float* b2   = (path==0)? hb_ : wb_;
  float* outp       = (path==0)? ah : aw;

  float in[CM];
#pragma unroll
  for (int c=0;c<CM;c++) in[c] = pool[(b*CM+c)*HH + tid];
#pragma unroll
  for (int gI=0;gI<4;gI++)
#pragma unroll
    for (int o=0;o<MG;o++){
      float s=0.f;
#pragma unroll
      for (int i=0;i<MG;i++) s = fmaf(w1[gI*64+o*8+i], in[gI*8+i], s);
      T[gI*8+o][tid] = s;
    }
  __syncthreads();
  if (tid < CM){
    float s=0.f, q=0.f;
    for (int k=0;k<HH;k++){ float t=T[tid][k]; s+=t; q+=t*t; }
    float mu = s*(1.0f/HH);
    float var = q*(1.0f/HH) - mu*mu;
    float a = rsqrtf(var+EPSF)*g1[tid];
    sa[tid]=a; sb[tid]=b1[tid]-mu*a;
  }
  __syncthreads();
  float z[CM];
  {
    float sil[CM];
#pragma unroll
    for (int c=0;c<CM;c++){
      float val = fmaf(T[c][tid], sa[c], sb[c]);
      sil[c] = val/(1.f+__expf(-val));
    }
#pragma unroll
    for (int gI=0;gI<4;gI++)
#pragma unroll
      for (int o=0;o<MG;o++){
        float s=b2[gI*8+o];
#pragma unroll
        for (int i=0;i<MG;i++) s = fmaf(w2[gI*64+o*8+i], sil[gI*8+i], s);
        z[gI*8+o]=s;
      }
  }
  __syncthreads();
#pragma unroll
  for (int c=0;c<CM;c++) T[c][tid]=z[c];
  __syncthreads();
  if (tid < CM){
    float mx=-1e30f;
    for (int k=0;k<HH;k++) mx = fmaxf(mx, T[tid][k]);
    float s=0.f;
    for (int k=0;k<HH;k++) s += __expf(T[tid][k]-mx);
    smx[tid]=mx; ssc[tid]=(float)HH/s;
  }
  __syncthreads();
#pragma unroll
  for (int c=0;c<CM;c++)
    outp[(b*CM+c)*HH + tid] = __expf(T[c][tid]-smx[c])*ssc[c];
}

// CoT part 1: att_pre only (+ att stats). k1/v recomputed later.
__global__ __launch_bounds__(256) void k_cot1(
  const float* __restrict__ y, const float* __restrict__ A, const float* __restrict__ Bo,
  const float* __restrict__ kw, const float* __restrict__ a1w,
  float* __restrict__ ao, float* __restrict__ s1, float* __restrict__ s2)
{
  int tid=threadIdx.x;
  int b = blockIdx.x >> 6;
  int p = ((blockIdx.x&63)<<8)+tid;
  size_t base = ((size_t)b*CM)*HWSZ + p;
  float xc[CM], k1[CM], at[CM];
#pragma unroll
  for (int c=0;c<CM;c++)
    xc[c] = fmaxf(0.f, fmaf(y[base+(size_t)c*HWSZ], A[b*CM+c], Bo[b*CM+c]));
#pragma unroll
  for (int gI=0;gI<4;gI++)
#pragma unroll
    for (int o=0;o<MG;o++){
      float sk=0.f;
#pragma unroll
      for (int i=0;i<MG;i++) sk = fmaf(kw[gI*64+o*8+i], xc[gI*MG+i], sk);
      k1[gI*MG+o]=sk;
    }
#pragma unroll
  for (int gI=0;gI<4;gI++)
#pragma unroll
    for (int o=0;o<MG;o++){
      float s=0.f;
#pragma unroll
      for (int i=0;i<16;i++){
        float inp = (gI<2) ? k1[gI*16+i] : xc[(gI-2)*16+i];
        s = fmaf(a1w[gI*128+o*16+i], inp, s);
      }
      at[gI*MG+o]=s;
    }
#pragma unroll
  for (int c=0;c<CM;c++) ao[base+(size_t)c*HWSZ]=at[c];
  float ms=0.f,mq=0.f;
#pragma unroll
  for (int c=0;c<CM;c++){
    float s=wsum(at[c]); float q=wsum(at[c]*at[c]);
    if ((tid&63)==c){ms=s;mq=q;}
  }
  int lane=tid&63;
  if (lane<CM){ atomicAdd(&s1[b*CM+lane],ms); atomicAdd(&s2[b*CM+lane],mq); }
}

// CoT part 2: softmax denominator only
__global__ __launch_bounds__(256) void k_cot2(
  const float* __restrict__ ao, const float* __restrict__ A, const float* __restrict__ Bo,
  const float* __restrict__ a2w, float* __restrict__ es)
{
  int tid=threadIdx.x;
  int b = blockIdx.x >> 6;
  int p = ((blockIdx.x&63)<<8)+tid;
  size_t base = ((size_t)b*CM)*HWSZ + p;
  float att[CM], l[CM];
#pragma unroll
  for (int c=0;c<CM;c++)
    att[c] = fmaxf(0.f, fmaf(ao[base+(size_t)c*HWSZ], A[b*CM+c], Bo[b*CM+c]));
#pragma unroll
  for (int gI=0;gI<4;gI++)
#pragma unroll
    for (int o=0;o<MG;o++){
      float s=0.f;
#pragma unroll
      for (int i=0;i<MG;i++) s = fmaf(a2w[gI*64+o*8+i], att[gI*8+i], s);
      l[gI*MG+o]=s;
    }
  float ms=0.f;
#pragma unroll
  for (int c=0;c<CM;c++){
    float s = wsum(__expf(l[c]*COT_ITAU));
    if ((tid&63)==c) ms=s;
  }
  int lane=tid&63;
  if (lane<CM) atomicAdd(&es[b*CM+lane], ms);
}

// recompute k1/v/logits, mix + cot_fuse + coord combine + fusion conv (+ fus stats)
__global__ __launch_bounds__(256) void k_mix_fuse(
  const float* __restrict__ y, const float* __restrict__ A, const float* __restrict__ Bo,
  const float* __restrict__ ao, const float* __restrict__ attA, const float* __restrict__ attB,
  const float* __restrict__ kw, const float* __restrict__ vw, const float* __restrict__ a2w,
  const float* __restrict__ ah, const float* __restrict__ awp, const float* __restrict__ es,
  const float* __restrict__ alpha, const float* __restrict__ beta,
  const float* __restrict__ fw, const float* __restrict__ fuw,
  float* __restrict__ fpo, float* __restrict__ s1, float* __restrict__ s2)
{
  int tid=threadIdx.x;
  int b = blockIdx.x>>6;
  int p = ((blockIdx.x&63)<<8)+tid;
  int h = p >> 7, w = p & (WW-1);
  size_t base = ((size_t)b*CM)*HWSZ + p;
  float al=alpha[0], be=beta[0];
  float xc[CM], att[CM], l[CM], t[CM];
#pragma unroll
  for (int c=0;c<CM;c++)
    xc[c] = fmaxf(0.f, fmaf(y[base+(size_t)c*HWSZ], A[b*CM+c], Bo[b*CM+c]));
#pragma unroll
  for (int c=0;c<CM;c++)
    att[c] = fmaxf(0.f, fmaf(ao[base+(size_t)c*HWSZ], attA[b*CM+c], attB[b*CM+c]));
#pragma unroll
  for (int gI=0;gI<4;gI++)
#pragma unroll
    for (int o=0;o<MG;o++){
      float s=0.f;
#pragma unroll
      for (int i=0;i<MG;i++) s = fmaf(a2w[gI*64+o*8+i], att[gI*8+i], s);
      l[gI*MG+o]=s;
    }
  // k1, v, then t = k1 + mix*v
#pragma unroll
  for (int gI=0;gI<4;gI++)
#pragma unroll
    for (int o=0;o<MG;o++){
      float sk=0.f, sv=0.f;
#pragma unroll
      for (int i=0;i<MG;i++){
        float xv = xc[gI*MG+i];
        sk = fmaf(kw[gI*64+o*8+i], xv, sk);
        sv = fmaf(vw[gI*64+o*8+i], xv, sv);
      }
      int c = gI*MG+o;
      float lgv = l[c];
      float sm = __expf(lgv*COT_ITAU) * (16384.f/es[b*CM+c]);
      float sg = 1.f/(1.f+__expf(-lgv));
      float mix = (1.f-LAM)*sg + LAM*sm;
      t[c] = fmaf(mix, sv, sk);
    }
  float co[CM];
#pragma unroll
  for (int c=0;c<CM;c++){
    float wl = al*ah[(b*CM+c)*HH + h] + be*awp[(b*CM+c)*WW + w];
    co[c] = xc[c] * wl;   // kappa = 1
  }
  float cot[CM];
#pragma unroll
  for (int o=0;o<CM;o++){
    float s=0.f;
#pragma unroll
    for (int i=0;i<CM;i++) s = fmaf(fw[o*CM+i], t[i], s);
    cot[o]=s;
  }
  float ms=0.f, mq=0.f;
#pragma unroll
  for (int o=0;o<CM;o++){
    float s=0.f;
#pragma unroll
    for (int i=0;i<CM;i++) s = fmaf(fuw[o*64+i], co[i], s);
#pragma unroll
    for (int i=0;i<CM;i++) s = fmaf(fuw[o*64+32+i], cot[i], s);
    fpo[base+(size_t)o*HWSZ]=s;
    float ss = wsum(s); float qq = wsum(s*s);
    if ((tid&63)==o){ ms=ss; mq=qq; }
  }
  int lane=tid&63;
  if (lane<CM){ atomicAdd(&s1[b*CM+lane],ms); atomicAdd(&s2[b*CM+lane],mq); }
}

// gate statistics: sum of relu(norm(fused_pre)) per (b,c)
__global__ __launch_bounds__(256) void k_gstat(const float4* __restrict__ fp,
  const float* __restrict__ A, const float* __restrict__ Bo, float* __restrict__ gsum)
{
  int idx = blockIdx.x*256+threadIdx.x;  // NB*CM*HWSZ/4
  int bc = idx >> 12;
  float a=A[bc], bb=Bo[bc];
  float4 tv = fp[idx];
  float s = fmaxf(0.f,fmaf(tv.x,a,bb))+fmaxf(0.f,fmaf(tv.y,a,bb))
          + fmaxf(0.f,fmaf(tv.z,a,bb))+fmaxf(0.f,fmaf(tv.w,a,bb));
  s = wsum(s);
  if ((threadIdx.x&63)==0) atomicAdd(&gsum[bc], s);
}

__global__ void k_gate(const float* __restrict__ gsum, const float* __restrict__ gw,
                       float* __restrict__ scale){
  int b = threadIdx.x;
  if (b < NB){
    float s=0.f;
    for (int c=0;c<CM;c++) s += gw[c]*gsum[b*CM+c];
    s *= (1.0f/HWSZ);
    float gt = 1.f/(1.f+__expf(-s));
    scale[b] = gt*(1.f-GFLOOR)+GFLOOR;
  }
}

// expand conv 32->512: float4 positions, 64 output channels per block
__global__ __launch_bounds__(256) void k_expand(const float4* __restrict__ fp4,
  const float* __restrict__ A, const float* __restrict__ Bo,
  const float* __restrict__ ew, const float* __restrict__ scale, float4* __restrict__ out4)
{
  int tid = threadIdx.x;
  int b = blockIdx.x >> 4;
  int tile = blockIdx.x & 15;
  int p4 = tile*256 + tid;            // float4 idx within batch plane (0..4095)
  int og = blockIdx.y * 64;
  float sc = scale[b];
  float4 f[CM];
  const float4* fb = fp4 + ((size_t)b*CM)*(HWSZ/4) + p4;
#pragma unroll
  for (int c=0;c<CM;c++){
    float4 t = fb[(size_t)c*(HWSZ/4)];
    float a=A[b*CM+c], bb=Bo[b*CM+c];
    f[c].x = fmaxf(0.f, fmaf(t.x,a,bb))*sc;
    f[c].y = fmaxf(0.f, fmaf(t.y,a,bb))*sc;
    f[c].z = fmaxf(0.f, fmaf(t.z,a,bb))*sc;
    f[c].w = fmaxf(0.f, fmaf(t.w,a,bb))*sc;
  }
  float4* ob = out4 + ((size_t)b*CIN + og)*(HWSZ/4) + p4;
  for (int j=0;j<64;j++){
    const float* wr = ew + (og+j)*CM;   // uniform -> scalar loads
    float4 acc; acc.x=0.f; acc.y=0.f; acc.z=0.f; acc.w=0.f;
#pragma unroll
    for (int c=0;c<CM;c++){
      float wv = wr[c];
      acc.x = fmaf(wv, f[c].x, acc.x);
      acc.y = fmaf(wv, f[c].y, acc.y);
      acc.z = fmaf(wv, f[c].z, acc.z);
      acc.w = fmaf(wv, f[c].w, acc.w);
    }
    ob[(size_t)j*(HWSZ/4)] = acc;
  }
}

extern "C" void kernel_launch(void* const* d_in, const int* in_sizes, int n_in,
                              void* d_out, int out_size, void* d_ws, size_t ws_size,
                              hipStream_t stream)
{
  const float* x    = (const float*)d_in[0];
  const float* cw   = (const float*)d_in[1];
  const float* incg = (const float*)d_in[2];
  const float* incb = (const float*)d_in[3];
  const float* pjw  = (const float*)d_in[4];
  const float* pjg  = (const float*)d_in[5];
  const float* pjb  = (const float*)d_in[6];
  const float* chw  = (const float*)d_in[7];
  const float* chb  = (const float*)d_in[8];
  const float* cww  = (const float*)d_in[9];
  const float* cwb  = (const float*)d_in[10];
  const float* alpha= (const float*)d_in[11];
  const float* beta = (const float*)d_in[12];
  const float* kw   = (const float*)d_in[13];
  const float* vw   = (const float*)d_in[14];
  const float* a1w  = (const float*)d_in[15];
  const float* ag   = (const float*)d_in[16];
  const float* ab   = (const float*)d_in[17];
  const float* a2w  = (const float*)d_in[18];
  const float* fw   = (const float*)d_in[19];
  const float* fuw  = (const float*)d_in[20];
  const float* fg   = (const float*)d_in[21];
  const float* fb   = (const float*)d_in[22];
  const float* gw   = (const float*)d_in[23];
  const float* ew   = (const float*)d_in[24];
  float* out = (float*)d_out;

  float* ws = (float*)d_ws;
  const size_t BIG = (size_t)NB*CM*HWSZ;  // 4,194,304 floats
  float* y    = ws;            // compressed pre-norm
  float* P    = ws +   BIG;    // att_pre
  float* F    = ws + 2*BIG;    // fused_pre; aliases part0 (dead before F written)
  float* part0= F;
  float* part1= ws + 3*BIG;
  float* sm   = ws + 4*BIG;
  float* wT    = sm;  sm += CM*CIN;
  float* hpool = sm;  sm += NB*CM*HH;
  float* wpool = sm;  sm += NB*CM*WW;
  float* ahB   = sm;  sm += NB*CM*HH;
  float* awB   = sm;  sm += NB*CM*WW;
  float* acc   = sm;  sm += 8*256;   // zeroed accumulators
  float* statS = acc,      *statQ = acc+256;
  float* attS  = acc+512,  *attQ  = acc+768;
  float* esum  = acc+1024;
  float* fusS  = acc+1280, *fusQ  = acc+1536;
  float* gsum  = acc+1792;
  float* normA = sm; sm+=256; float* normB = sm; sm+=256;
  float* attA  = sm; sm+=256; float* attB  = sm; sm+=256;
  float* fusA  = sm; sm+=256; float* fusB  = sm; sm+=256;
  float* scale = sm; sm+=64;

  hipMemsetAsync(acc, 0, 8*256*sizeof(float), stream);
  k_tw<<<64,256,0,stream>>>(cw, wT);
  k_compress<<<dim3(512,2),256,0,stream>>>(x, wT, part0);
  k_comb<<<4096,256,0,stream>>>((const float4*)part0,(const float4*)part1,(float4*)y,statS,statQ);
  k_finalize<<<1,256,0,stream>>>(statS,statQ,incg,incb,normA,normB,(float)HWSZ);
  k_pool_w<<<128,256,0,stream>>>(y,normA,normB,wpool);
  k_pool_h<<<8192,256,0,stream>>>(y,normA,normB,hpool);
  k_coord<<<16,128,0,stream>>>(hpool,wpool,pjw,pjg,pjb,chw,chb,cww,cwb,ahB,awB);
  k_cot1<<<512,256,0,stream>>>(y,normA,normB,kw,a1w,P,attS,attQ);
  k_finalize<<<1,256,0,stream>>>(attS,attQ,ag,ab,attA,attB,(float)HWSZ);
  k_cot2<<<512,256,0,stream>>>(P,attA,attB,a2w,esum);
  k_mix_fuse<<<512,256,0,stream>>>(y,normA,normB,P,attA,attB,kw,vw,a2w,ahB,awB,esum,alpha,beta,fw,fuw,F,fusS,fusQ);
  k_finalize<<<1,256,0,stream>>>(fusS,fusQ,fg,fb,fusA,fusB,(float)HWSZ);
  k_gstat<<<4096,256,0,stream>>>((const float4*)F, fusA,fusB,gsum);
  k_gate<<<1,64,0,stream>>>(gsum,gw,scale);
  k_expand<<<dim3(128,8),256,0,stream>>>((const float4*)F,fusA,fusB,ew,scale,(float4*)out);
}